// Round 2
// baseline (21403.561 us; speedup 1.0000x reference)
//
#include <hip/hip_runtime.h>
#include <stdint.h>

// Problem constants
#define T_LEN 1024
#define D_IN  128
#define HID   256
#define NCOL  1024   // 4*HID gate columns (g,i,f,o)
#define NB    8      // recurrent blocks (batch-split, zero inter-block sync)
#define BB    16     // batches per block (== MFMA M)
#define NCLS  10

// A-panel K layout (bf16): [0,128)=x_hi, [128,256)=x_lo, [256,512)=h  -> 16 k-tiles of 32
#define KA    512
#define ASTR  520    // A_lds stride (shorts), padded
#define GSTR  1026   // gate_lds stride (floats), padded (2 mod 32 -> 2-way max)
#define NBT   16     // B k-tiles per col-tile: 0-3 Wx_hi, 4-7 Wx_lo, 8-15 Wh

typedef __attribute__((ext_vector_type(8))) short s16x8;
typedef __attribute__((ext_vector_type(4))) float f32x4;
typedef __attribute__((ext_vector_type(4))) unsigned short u16x4;

__device__ __forceinline__ unsigned short f2bf(float f) {
    union { float f; uint32_t u; } v; v.f = f;
    uint32_t r = (v.u + 0x7FFFu + ((v.u >> 16) & 1u)) >> 16;
    return (unsigned short)r;
}
__device__ __forceinline__ float bf2f(unsigned short s) {
    union { uint32_t u; float f; } v; v.u = ((uint32_t)s) << 16;
    return v.f;
}
__device__ __forceinline__ float fsig(float x) {
    return __builtin_amdgcn_rcpf(1.0f + __builtin_amdgcn_exp2f(-1.44269504f * x));
}
__device__ __forceinline__ float ftanh(float x) {
    return 2.0f * __builtin_amdgcn_rcpf(1.0f + __builtin_amdgcn_exp2f(-2.88539008f * x)) - 1.0f;
}

// Pre-tile weights into exact per-lane MFMA B-fragment order.
// frag idx = ((w*8 + nt)*16 + bt)*64 + lane ; 8 bf16 each (16B, contiguous 1KB per wave frag).
// col = w*128 + nt*16 + (lane&15); ko = (lane>>4)*8 + e
// bt 0-3: Wx_hi  k=(bt&3)*32+ko   | bt 4-7: Wx_lo (residual) | bt 8-15: Wh k=(bt-8)*32+ko
__global__ void prep_kernel(const float* __restrict__ Wgx, const float* __restrict__ Wix,
                            const float* __restrict__ Wfx, const float* __restrict__ Wox,
                            const float* __restrict__ Wgh, const float* __restrict__ Wih,
                            const float* __restrict__ Wfh, const float* __restrict__ Woh,
                            const float* __restrict__ bg,  const float* __restrict__ bi,
                            const float* __restrict__ bf_, const float* __restrict__ bo,
                            unsigned short* __restrict__ WT, float* __restrict__ bias_ws) {
    int idx = blockIdx.x * 256 + threadIdx.x;   // 65536 threads, one 8-elem frag each
    int l  = idx & 63;
    int bt = (idx >> 6) & 15;
    int nt = (idx >> 10) & 7;
    int w  = (idx >> 13) & 7;
    int col = w * 128 + nt * 16 + (l & 15);
    int gate = col >> 8, u = col & 255;
    const float* wx = (gate == 0) ? Wgx : (gate == 1) ? Wix : (gate == 2) ? Wfx : Wox;
    const float* wh = (gate == 0) ? Wgh : (gate == 1) ? Wih : (gate == 2) ? Wfh : Woh;
    unsigned short out8[8];
#pragma unroll
    for (int e = 0; e < 8; ++e) {
        int ko = (l >> 4) * 8 + e;
        unsigned short r;
        if (bt < 8) {
            int k = (bt & 3) * 32 + ko;
            float v = wx[k * HID + u];
            unsigned short hi = f2bf(v);
            if (bt < 4) r = hi;
            else        r = f2bf(v - bf2f(hi));   // exact residual, then round
        } else {
            int k = (bt - 8) * 32 + ko;
            r = f2bf(wh[k * HID + u]);
        }
        out8[e] = r;
    }
    u16x4* dst = (u16x4*)(WT + (size_t)idx * 8);
    dst[0] = *(u16x4*)&out8[0];
    dst[1] = *(u16x4*)&out8[4];
    if (idx < NCOL) {
        int g2 = idx >> 8, u2 = idx & 255;
        const float* bb = (g2 == 0) ? bg : (g2 == 1) ? bi : (g2 == 2) ? bf_ : bo;
        bias_ws[idx] = bb[u2];
    }
}

#define MFMA(A, B) asm volatile("v_mfma_f32_16x16x32_bf16 %0, %1, %2, %0" \
                                : "+v"(acc) : "v"(A), "v"(B))

// 8 blocks x 512 threads. Block b: batches [16b,16b+16). Full 1024-step scan + projection.
__global__ __launch_bounds__(512) void lstm_kernel(
        const float* __restrict__ x, const unsigned short* __restrict__ WT,
        const float* __restrict__ bias_ws, const float* __restrict__ Wph,
        const float* __restrict__ bp, float* __restrict__ out) {
    __shared__ unsigned short A_lds[BB][ASTR];    // 16,640 B (x_hi | x_lo | h)
    __shared__ float          gate_lds[BB][GSTR]; // 65,664 B (fp32 pre-activations)
    __shared__ float          c_st[BB][HID];      // 16,384 B

    const int tid  = threadIdx.x;
    const int lane = tid & 63;
    const int wave = tid >> 6;            // 0..7
    const int b0   = blockIdx.x * BB;
    const int mrow = lane & 15;           // A-row (batch) / B,D-col index
    const int kq   = lane >> 4;           // 0..3

    // zero-init h and c
    for (int i = tid; i < BB * HID; i += 512) {
        int b = i >> 8, u = i & 255;
        A_lds[b][256 + u] = 0;
        c_st[b][u] = 0.0f;
    }

    // wave owns gate columns [128*wave, 128*wave+128)
    const int c0 = wave * 128;
    float bias_r[8];
#pragma unroll
    for (int nt = 0; nt < 8; ++nt) bias_r[nt] = bias_ws[c0 + nt * 16 + mrow];
    // per-wave fragment base: wave * 8nt * 16bt * 64lane * 8elem
    const unsigned short* wbase = WT + (size_t)wave * 65536 + (size_t)lane * 8;

    // x staging: thread -> (batch xb, dims xd..xd+3); prefetch t=0
    const int xb = tid >> 5;              // 0..15
    const int xd = (tid & 31) * 4;        // 0..124
    const float* xptr = x + ((size_t)(b0 + xb) * T_LEN) * D_IN + xd;
    float4 xv = *(const float4*)(xptr);

    for (int t = 0; t < T_LEN; ++t) {
        // stage x_t (hi+lo split), prefetch x_{t+1}
        {
            u16x4 hv, lv;
            unsigned short h0 = f2bf(xv.x); hv.x = h0; lv.x = f2bf(xv.x - bf2f(h0));
            unsigned short h1 = f2bf(xv.y); hv.y = h1; lv.y = f2bf(xv.y - bf2f(h1));
            unsigned short h2 = f2bf(xv.z); hv.z = h2; lv.z = f2bf(xv.z - bf2f(h2));
            unsigned short h3 = f2bf(xv.w); hv.w = h3; lv.w = f2bf(xv.w - bf2f(h3));
            *(u16x4*)&A_lds[xb][xd]       = hv;
            *(u16x4*)&A_lds[xb][128 + xd] = lv;
            int tn = (t + 1 < T_LEN) ? (t + 1) : (T_LEN - 1);
            xv = *(const float4*)(xptr + (size_t)tn * D_IN);
        }
        __syncthreads();

        // A-fragments: 16 k-tiles (x_hi 0-3, x_lo 4-7, h 8-15), reused across 8 N-tiles
        s16x8 a[16];
#pragma unroll
        for (int at = 0; at < 16; ++at)
            a[at] = *(const s16x8*)&A_lds[mrow][at * 32 + kq * 8];

#pragma unroll
        for (int nt = 0; nt < 8; ++nt) {
            f32x4 acc = { bias_r[nt], bias_r[nt], bias_r[nt], bias_r[nt] };
            const unsigned short* wp = wbase + nt * 8192;   // 16bt*64*8 per nt
#pragma unroll
            for (int j = 0; j < 4; ++j) {                   // Wx_hi: used by x_hi AND x_lo
                s16x8 bfr = *(const s16x8*)(wp + j * 512);
                MFMA(a[j], bfr);
                MFMA(a[4 + j], bfr);
            }
#pragma unroll
            for (int j = 0; j < 4; ++j) {                   // Wx_lo: x_hi only
                s16x8 bfr = *(const s16x8*)(wp + (4 + j) * 512);
                MFMA(a[j], bfr);
            }
#pragma unroll
            for (int j = 0; j < 8; ++j) {                   // Wh: h
                s16x8 bfr = *(const s16x8*)(wp + (8 + j) * 512);
                MFMA(a[8 + j], bfr);
            }
            asm volatile("s_nop 7\n\ts_nop 7" ::: );        // MFMA->reader hazard pad
            int col = c0 + nt * 16 + mrow;
#pragma unroll
            for (int r = 0; r < 4; ++r)
                gate_lds[kq * 4 + r][col] = acc[r];
        }
        __syncthreads();

        // elementwise LSTM cell update (fp32 gates): thread -> (b, u+32jj)
        {
            int u = tid & 31;
            int b = tid >> 5;
#pragma unroll
            for (int jj = 0; jj < 8; ++jj, u += 32) {
                float pg = gate_lds[b][u];
                float pi = gate_lds[b][u + 256];
                float pf = gate_lds[b][u + 512];
                float po = gate_lds[b][u + 768];
                float g  = ftanh(pg);
                float ig = fsig(pi);
                float fg = fsig(pf);
                float og = fsig(po);
                float c  = g * ig + c_st[b][u] * fg;
                c_st[b][u] = c;
                float h  = ftanh(c) * og;
                A_lds[b][256 + u] = f2bf(h);
            }
        }
        __syncthreads();
    }

    // final projection: out[b][cls] = sum_u h[b][u] * Wph[u][cls] + bp[cls]
    if (tid < BB * NCLS) {
        int b = tid / NCLS, cls = tid - b * NCLS;
        float acc = bp[cls];
        for (int u = 0; u < HID; ++u)
            acc += bf2f(A_lds[b][256 + u]) * Wph[u * NCLS + cls];
        out[(b0 + b) * NCLS + cls] = acc;
    }
}

extern "C" void kernel_launch(void* const* d_in, const int* in_sizes, int n_in,
                              void* d_out, int out_size, void* d_ws, size_t ws_size,
                              hipStream_t stream) {
    const float* x   = (const float*)d_in[0];
    const float* Wgx = (const float*)d_in[1];
    const float* Wgh = (const float*)d_in[2];
    const float* bg  = (const float*)d_in[3];
    const float* Wix = (const float*)d_in[4];
    const float* Wih = (const float*)d_in[5];
    const float* bi  = (const float*)d_in[6];
    const float* Wfx = (const float*)d_in[7];
    const float* Wfh = (const float*)d_in[8];
    const float* bf_ = (const float*)d_in[9];
    const float* Wox = (const float*)d_in[10];
    const float* Woh = (const float*)d_in[11];
    const float* bo  = (const float*)d_in[12];
    const float* Wph = (const float*)d_in[13];
    const float* bp  = (const float*)d_in[14];

    unsigned short* WT = (unsigned short*)d_ws;                 // 65536 frags * 16B = 1 MB
    float* bias_ws = (float*)((char*)d_ws + (size_t)65536 * 16); // +4 KB

    prep_kernel<<<256, 256, 0, stream>>>(
        Wgx, Wix, Wfx, Wox, Wgh, Wih, Wfh, Woh, bg, bi, bf_, bo, WT, bias_ws);
    lstm_kernel<<<NB, 512, 0, stream>>>(x, WT, bias_ws, Wph, bp, (float*)d_out);
}

// Round 3
// 10336.838 us; speedup vs baseline: 2.0706x; 2.0706x over previous
//
#include <hip/hip_runtime.h>
#include <stdint.h>

// Problem constants
#define T_LEN 1024
#define D_IN  128
#define HID   256
#define NCLS  10
#define NGRP  8      // batch groups (16 batches each)
#define NCB   8      // column-blocks per group (32 units each)
#define BB    16     // batches per group (== MFMA M)

// Workspace layout (bytes)
#define WT_BYTES   (8*8*16*64*8*2)          // 1,048,576: pre-tiled B-fragments
#define BIAS_OFF   WT_BYTES                 // 1024 fp32 = 4 KB
#define FLAGS_OFF  (BIAS_OFF + 4096)        // 8g*8j*16 u32 = 4 KB
#define HBUF_OFF   (FLAGS_OFF + 4096)       // 2 slots * 8g * 8j * 128 u64 = 128 KB

typedef __attribute__((ext_vector_type(8))) short s16x8;
typedef __attribute__((ext_vector_type(4))) float f32x4;
typedef __attribute__((ext_vector_type(4))) unsigned short u16x4;
typedef unsigned long long u64;

__device__ __forceinline__ unsigned short f2bf(float f) {
    union { float f; uint32_t u; } v; v.f = f;
    return (unsigned short)((v.u + 0x7FFFu + ((v.u >> 16) & 1u)) >> 16);
}
__device__ __forceinline__ float bf2f(unsigned short s) {
    union { uint32_t u; float f; } v; v.u = ((uint32_t)s) << 16;
    return v.f;
}
__device__ __forceinline__ float fsig(float x) {
    return __builtin_amdgcn_rcpf(1.0f + __builtin_amdgcn_exp2f(-1.44269504f * x));
}
__device__ __forceinline__ float ftanh(float x) {
    return 2.0f * __builtin_amdgcn_rcpf(1.0f + __builtin_amdgcn_exp2f(-2.88539008f * x)) - 1.0f;
}

// Pre-tile weights into per-(colblock j, wave w) register-fragment order.
// frag idx = ((j*8 + w)*16 + bt)*64 + lane, 8 bf16 each.
// global col = (w>>1)*256 + 32*j + (w&1)*16 + (lane&15); ko = (lane>>4)*8 + e
// bt 0-3: Wx_hi k=bt*32+ko | bt 4-7: Wx_lo residual | bt 8-15: Wh k=(bt-8)*32+ko
__global__ void prep_kernel(const float* __restrict__ Wgx, const float* __restrict__ Wix,
                            const float* __restrict__ Wfx, const float* __restrict__ Wox,
                            const float* __restrict__ Wgh, const float* __restrict__ Wih,
                            const float* __restrict__ Wfh, const float* __restrict__ Woh,
                            const float* __restrict__ bg,  const float* __restrict__ bi,
                            const float* __restrict__ bf_, const float* __restrict__ bo,
                            const float* __restrict__ bp,
                            unsigned short* __restrict__ WT, float* __restrict__ bias_ws,
                            unsigned int* __restrict__ flags, float* __restrict__ out) {
    int idx = blockIdx.x * 256 + threadIdx.x;   // 65536 threads
    int l  = idx & 63;
    int bt = (idx >> 6) & 15;
    int w  = (idx >> 10) & 7;
    int j  = (idx >> 13) & 7;
    int col = (w >> 1) * 256 + 32 * j + (w & 1) * 16 + (l & 15);
    int gate = col >> 8, u = col & 255;
    const float* wx = (gate == 0) ? Wgx : (gate == 1) ? Wix : (gate == 2) ? Wfx : Wox;
    const float* wh = (gate == 0) ? Wgh : (gate == 1) ? Wih : (gate == 2) ? Wfh : Woh;
    unsigned short o8[8];
#pragma unroll
    for (int e = 0; e < 8; ++e) {
        int ko = (l >> 4) * 8 + e;
        unsigned short r;
        if (bt < 8) {
            int k = (bt & 3) * 32 + ko;
            float v = wx[k * HID + u];
            unsigned short hi = f2bf(v);
            r = (bt < 4) ? hi : f2bf(v - bf2f(hi));
        } else {
            r = f2bf(wh[((bt - 8) * 32 + ko) * HID + u]);
        }
        o8[e] = r;
    }
    u16x4* dst = (u16x4*)(WT + (size_t)idx * 8);
    dst[0] = *(u16x4*)&o8[0];
    dst[1] = *(u16x4*)&o8[4];

    if (idx < 1024) {                    // bias by global column
        int g2 = idx >> 8, u2 = idx & 255;
        const float* bb = (g2 == 0) ? bg : (g2 == 1) ? bi : (g2 == 2) ? bf_ : bo;
        bias_ws[idx] = bb[u2];
    } else if (idx < 2048) {             // zero sequence flags
        flags[idx - 1024] = 0;
    } else if (idx < 2048 + BB * NGRP * NCLS) {  // init out with bias
        int i2 = idx - 2048;
        out[i2] = bp[i2 % NCLS];
    }
}

#define MFMA(A, B) asm volatile("v_mfma_f32_16x16x32_bf16 %0, %1, %2, %0" \
                                : "+v"(acc) : "v"(A), "v"(B))

// 64 blocks x 512 threads. Block (g=bid&7, j=bid>>3): batch group g, units [32j,32j+32).
__global__ __launch_bounds__(512, 2) void lstm_kernel(
        const float* __restrict__ x, const unsigned short* __restrict__ WT,
        const float* __restrict__ bias_ws, const float* __restrict__ Wph,
        unsigned int* __restrict__ flags, u64* __restrict__ hbuf,
        float* __restrict__ out) {
    __shared__ unsigned short A_lds[BB][520];   // [0,128)=x_hi [128,256)=x_lo [256,512)=h(global units)
    __shared__ float gate_lds[BB][132];         // 128 local cols: [g(0-31) i f o]

    const int tid  = threadIdx.x;
    const int lane = tid & 63;
    const int w    = tid >> 6;                  // wave 0..7
    const int g    = blockIdx.x & 7;            // batch group (same-XCD pairing under %8 round-robin)
    const int j    = blockIdx.x >> 3;           // column-block
    const int mrow = lane & 15;
    const int kq   = lane >> 4;

    for (int i = tid; i < BB * 520; i += 512) ((unsigned short*)A_lds)[i] = 0;

    // whole weight slice -> 64 VGPRs/lane, resident for all 1024 steps
    s16x8 B[16];
    {
        const unsigned short* wp = WT + ((size_t)((j * 8 + w) * 16) * 64 + lane) * 8;
#pragma unroll
        for (int bt = 0; bt < 16; ++bt) B[bt] = *(const s16x8*)(wp + (size_t)bt * 512);
    }
    const int gcol = (w >> 1) * 256 + 32 * j + (w & 1) * 16 + mrow;
    const float bias_r = bias_ws[gcol];

    // x staging map: thread -> (batch xb, dims xd..xd+3); prefetch t=0
    const int xb = tid >> 5;
    const int xd = (tid & 31) * 4;
    const float* xptr = x + ((size_t)(g * BB + xb) * T_LEN) * D_IN + xd;
    float4 xv = *(const float4*)xptr;

    const int b_e = tid >> 5, u_e = tid & 31;   // elementwise: (batch, rel-unit)
    float c_reg = 0.0f;

    unsigned int* myflag = flags + (size_t)(g * 8 + j) * 16 + w;

    for (int t = 0; t < T_LEN; ++t) {
        // stage x_t (hi/lo), prefetch x_{t+1}
        {
            u16x4 hv, lv;
            unsigned short h0 = f2bf(xv.x); hv.x = h0; lv.x = f2bf(xv.x - bf2f(h0));
            unsigned short h1 = f2bf(xv.y); hv.y = h1; lv.y = f2bf(xv.y - bf2f(h1));
            unsigned short h2 = f2bf(xv.z); hv.z = h2; lv.z = f2bf(xv.z - bf2f(h2));
            unsigned short h3 = f2bf(xv.w); hv.w = h3; lv.w = f2bf(xv.w - bf2f(h3));
            *(u16x4*)&A_lds[xb][xd]       = hv;
            *(u16x4*)&A_lds[xb][128 + xd] = lv;
            int tn = (t + 1 < T_LEN) ? (t + 1) : (T_LEN - 1);
            xv = *(const float4*)(xptr + (size_t)tn * D_IN);
        }
        // gather partners' h[t-1] (wave w handles partner (j+w)&7; wave 0 idle)
        if (t > 0 && w > 0) {
            const int pj = (j + w) & 7;
            const unsigned int* pf = flags + (size_t)(g * 8 + pj) * 16;
            if (lane < 8) {
                while (__hip_atomic_load(&pf[lane], __ATOMIC_ACQUIRE,
                                         __HIP_MEMORY_SCOPE_AGENT) < (unsigned)t) { }
            }
            const u64* hb = hbuf + ((size_t)((t - 1) & 1) * 64 + g * 8 + pj) * 128;
            u64 v0 = __hip_atomic_load(&hb[lane],      __ATOMIC_RELAXED, __HIP_MEMORY_SCOPE_AGENT);
            u64 v1 = __hip_atomic_load(&hb[64 + lane], __ATOMIC_RELAXED, __HIP_MEMORY_SCOPE_AGENT);
            *(u64*)&A_lds[lane >> 3][256 + 32 * pj + 4 * (lane & 7)]       = v0;
            *(u64*)&A_lds[8 + (lane >> 3)][256 + 32 * pj + 4 * (lane & 7)] = v1;
        }
        __syncthreads();

        // A-frags (shared by all waves) + MFMA from register-resident weights
        s16x8 a[16];
#pragma unroll
        for (int at = 0; at < 16; ++at)
            a[at] = *(const s16x8*)&A_lds[mrow][at * 32 + kq * 8];
        f32x4 acc = { bias_r, bias_r, bias_r, bias_r };
#pragma unroll
        for (int q = 0; q < 4; ++q) {
            MFMA(a[q], B[q]);           // x_hi * Wx_hi
            MFMA(a[4 + q], B[q]);       // x_lo * Wx_hi
            MFMA(a[q], B[4 + q]);       // x_hi * Wx_lo
        }
#pragma unroll
        for (int q = 8; q < 16; ++q) MFMA(a[q], B[q]);   // h * Wh
        asm volatile("s_nop 7\n\ts_nop 7" ::: );
#pragma unroll
        for (int r = 0; r < 4; ++r)
            gate_lds[kq * 4 + r][w * 16 + mrow] = acc[r];
        __syncthreads();

        // elementwise cell update (c thread-private fp32)
        float pg  = gate_lds[b_e][u_e];
        float pi  = gate_lds[b_e][32 + u_e];
        float pff = gate_lds[b_e][64 + u_e];
        float po  = gate_lds[b_e][96 + u_e];
        c_reg = ftanh(pg) * fsig(pi) + c_reg * fsig(pff);
        float h = ftanh(c_reg) * fsig(po);
        unsigned int hb16 = f2bf(h);
        A_lds[b_e][256 + 32 * j + u_e] = (unsigned short)hb16;

        // pack 4 lanes -> u64, publish own slice, release per-wave flag
        unsigned int p01 = hb16 | (((unsigned int)__shfl_down((int)hb16, 1)) << 16);
        unsigned int p23 = (unsigned int)__shfl_down((int)p01, 2);
        u64 val = (u64)p01 | ((u64)p23 << 32);
        if ((lane & 3) == 0) {
            u64* dst = hbuf + ((size_t)(t & 1) * 64 + g * 8 + j) * 128 + (b_e * 8 + (u_e >> 2));
            __hip_atomic_store(dst, val, __ATOMIC_RELAXED, __HIP_MEMORY_SCOPE_AGENT);
        }
        asm volatile("s_waitcnt vmcnt(0)" ::: "memory");   // wave-level drain of data stores
        if (lane == 0)
            __hip_atomic_store(myflag, (unsigned int)(t + 1), __ATOMIC_RELEASE,
                               __HIP_MEMORY_SCOPE_AGENT);
    }
    __syncthreads();

    // projection partial over own 32 units -> atomicAdd into bias-initialized out
    if (tid < BB * NCLS) {
        int b = tid / NCLS, cls = tid - b * NCLS;
        float s = 0.0f;
#pragma unroll
        for (int u = 0; u < 32; ++u)
            s += bf2f(A_lds[b][256 + 32 * j + u]) * Wph[(32 * j + u) * NCLS + cls];
        atomicAdd(&out[(g * BB + b) * NCLS + cls], s);
    }
}

extern "C" void kernel_launch(void* const* d_in, const int* in_sizes, int n_in,
                              void* d_out, int out_size, void* d_ws, size_t ws_size,
                              hipStream_t stream) {
    const float* x   = (const float*)d_in[0];
    const float* Wgx = (const float*)d_in[1];
    const float* Wgh = (const float*)d_in[2];
    const float* bg  = (const float*)d_in[3];
    const float* Wix = (const float*)d_in[4];
    const float* Wih = (const float*)d_in[5];
    const float* bi  = (const float*)d_in[6];
    const float* Wfx = (const float*)d_in[7];
    const float* Wfh = (const float*)d_in[8];
    const float* bf_ = (const float*)d_in[9];
    const float* Wox = (const float*)d_in[10];
    const float* Woh = (const float*)d_in[11];
    const float* bo  = (const float*)d_in[12];
    const float* Wph = (const float*)d_in[13];
    const float* bp  = (const float*)d_in[14];

    unsigned short* WT  = (unsigned short*)d_ws;
    float* bias_ws      = (float*)((char*)d_ws + BIAS_OFF);
    unsigned int* flags = (unsigned int*)((char*)d_ws + FLAGS_OFF);
    u64* hbuf           = (u64*)((char*)d_ws + HBUF_OFF);

    prep_kernel<<<256, 256, 0, stream>>>(
        Wgx, Wix, Wfx, Wox, Wgh, Wih, Wfh, Woh, bg, bi, bf_, bo, bp,
        WT, bias_ws, flags, (float*)d_out);
    lstm_kernel<<<NGRP * NCB, 512, 0, stream>>>(
        x, WT, bias_ws, Wph, flags, hbuf, (float*)d_out);
}

// Round 5
// 2479.281 us; speedup vs baseline: 8.6330x; 4.1693x over previous
//
#include <hip/hip_runtime.h>
#include <stdint.h>

// Problem constants
#define T_LEN 1024
#define D_IN  128
#define HID   256
#define NCLS  10
#define NGRP  8      // batch groups (16 batches each)
#define NCB   8      // column-blocks per group (32 units each)
#define BB    16     // batches per group (== MFMA M)

// Workspace layout (bytes)
#define WT_BYTES   (8*8*16*64*8*2)          // 1,048,576: pre-tiled B-fragments
#define BIAS_OFF   WT_BYTES                 // 1024 fp32 = 4 KB
#define FLAGS_OFF  (BIAS_OFF + 4096)        // 8g*8j*16 u32 = 4 KB
#define HBUF_OFF   (FLAGS_OFF + 4096)       // 2 slots * 8g * 8j * 128 u64 = 128 KB

typedef __attribute__((ext_vector_type(8))) short s16x8;
typedef __attribute__((ext_vector_type(4))) float f32x4;
typedef __attribute__((ext_vector_type(4))) unsigned short u16x4;
typedef unsigned long long u64;

__device__ __forceinline__ unsigned short f2bf(float f) {
    union { float f; uint32_t u; } v; v.f = f;
    return (unsigned short)((v.u + 0x7FFFu + ((v.u >> 16) & 1u)) >> 16);
}
__device__ __forceinline__ float bf2f(unsigned short s) {
    union { uint32_t u; float f; } v; v.u = ((uint32_t)s) << 16;
    return v.f;
}
__device__ __forceinline__ float fsig(float x) {
    return __builtin_amdgcn_rcpf(1.0f + __builtin_amdgcn_exp2f(-1.44269504f * x));
}
__device__ __forceinline__ float ftanh(float x) {
    return 2.0f * __builtin_amdgcn_rcpf(1.0f + __builtin_amdgcn_exp2f(-2.88539008f * x)) - 1.0f;
}

// Pre-tile weights into per-(colblock j, wave w) register-fragment order.
// frag idx = ((j*8 + w)*16 + bt)*64 + lane, 8 bf16 each.
// global col = (w>>1)*256 + 32*j + (w&1)*16 + (lane&15); ko = (lane>>4)*8 + e
// bt 0-3: Wx_hi k=bt*32+ko | bt 4-7: Wx_lo residual | bt 8-15: Wh k=(bt-8)*32+ko
__global__ void prep_kernel(const float* __restrict__ Wgx, const float* __restrict__ Wix,
                            const float* __restrict__ Wfx, const float* __restrict__ Wox,
                            const float* __restrict__ Wgh, const float* __restrict__ Wih,
                            const float* __restrict__ Wfh, const float* __restrict__ Woh,
                            const float* __restrict__ bg,  const float* __restrict__ bi,
                            const float* __restrict__ bf_, const float* __restrict__ bo,
                            const float* __restrict__ bp,
                            unsigned short* __restrict__ WT, float* __restrict__ bias_ws,
                            unsigned int* __restrict__ flags, float* __restrict__ out) {
    int idx = blockIdx.x * 256 + threadIdx.x;   // 65536 threads
    int l  = idx & 63;
    int bt = (idx >> 6) & 15;
    int w  = (idx >> 10) & 7;
    int j  = (idx >> 13) & 7;
    int col = (w >> 1) * 256 + 32 * j + (w & 1) * 16 + (l & 15);
    int gate = col >> 8, u = col & 255;
    const float* wx = (gate == 0) ? Wgx : (gate == 1) ? Wix : (gate == 2) ? Wfx : Wox;
    const float* wh = (gate == 0) ? Wgh : (gate == 1) ? Wih : (gate == 2) ? Wfh : Woh;
    unsigned short o8[8];
#pragma unroll
    for (int e = 0; e < 8; ++e) {
        int ko = (l >> 4) * 8 + e;
        unsigned short r;
        if (bt < 8) {
            int k = (bt & 3) * 32 + ko;
            float v = wx[k * HID + u];
            unsigned short hi = f2bf(v);
            r = (bt < 4) ? hi : f2bf(v - bf2f(hi));
        } else {
            r = f2bf(wh[((bt - 8) * 32 + ko) * HID + u]);
        }
        o8[e] = r;
    }
    u16x4* dst = (u16x4*)(WT + (size_t)idx * 8);
    dst[0] = *(u16x4*)&o8[0];
    dst[1] = *(u16x4*)&o8[4];

    if (idx < 1024) {                    // bias by global column
        int g2 = idx >> 8, u2 = idx & 255;
        const float* bb = (g2 == 0) ? bg : (g2 == 1) ? bi : (g2 == 2) ? bf_ : bo;
        bias_ws[idx] = bb[u2];
    } else if (idx < 2048) {             // zero sequence flags
        flags[idx - 1024] = 0;
    } else if (idx < 2048 + BB * NGRP * NCLS) {  // init out with bias
        int i2 = idx - 2048;
        out[i2] = bp[i2 % NCLS];
    }
}

// MFMA with A-frag in VGPR, B-frag pinned in AGPR
#define MFMA_A(Aop, Bop) asm volatile("v_mfma_f32_16x16x32_bf16 %0, %1, %2, %0" \
                                      : "+v"(acc) : "v"(Aop), "a"(Bop))

// 64 blocks x 512 threads. Block (g=bid&7, j=bid>>3): batch group g, units [32j,32j+32).
__global__ __launch_bounds__(512, 2) void lstm_kernel(
        const float* __restrict__ x, const unsigned short* __restrict__ WT,
        const float* __restrict__ bias_ws, const float* __restrict__ Wph,
        unsigned int* __restrict__ flags, u64* __restrict__ hbuf,
        float* __restrict__ out) {
    __shared__ unsigned short A_lds[BB][520];   // [0,128)=x_hi [128,256)=x_lo [256,512)=h(global units)
    __shared__ float gate_lds[BB][132];         // 128 local cols: [g(0-31) i f o]

    const int tid  = threadIdx.x;
    const int lane = tid & 63;
    const int w    = tid >> 6;                  // wave 0..7
    const int g    = blockIdx.x & 7;            // batch group (same-XCD pairing under %8 round-robin)
    const int j    = blockIdx.x >> 3;           // column-block
    const int mrow = lane & 15;
    const int kq   = lane >> 4;

    for (int i = tid; i < BB * 520; i += 512) ((unsigned short*)A_lds)[i] = 0;

    // whole weight slice -> 64 AGPRs/lane, pinned resident for all 1024 steps
    s16x8 Bf[16];
    {
        const unsigned short* wp = WT + ((size_t)((j * 8 + w) * 16) * 64 + lane) * 8;
#pragma unroll
        for (int bt = 0; bt < 16; ++bt) Bf[bt] = *(const s16x8*)(wp + (size_t)bt * 512);
    }
#pragma unroll
    for (int bt = 0; bt < 16; ++bt)
        asm volatile("" : "+a"(Bf[bt]));        // home the weight slice in AGPRs

    const int gcol = (w >> 1) * 256 + 32 * j + (w & 1) * 16 + mrow;
    const float bias_r = bias_ws[gcol];

    // x staging map: thread -> (batch xb, dims xd..xd+3); prefetch t=0
    const int xb = tid >> 5;
    const int xd = (tid & 31) * 4;
    const float* xptr = x + ((size_t)(g * BB + xb) * T_LEN) * D_IN + xd;
    float4 xv = *(const float4*)xptr;

    const int b_e = tid >> 5, u_e = tid & 31;   // elementwise: (batch, rel-unit)
    float c_reg = 0.0f;

    unsigned int* myflag = flags + (size_t)(g * 8 + j) * 16 + w;

    for (int t = 0; t < T_LEN; ++t) {
        // stage x_t (hi/lo), prefetch x_{t+1}
        {
            u16x4 hv, lv;
            unsigned short h0 = f2bf(xv.x); hv.x = h0; lv.x = f2bf(xv.x - bf2f(h0));
            unsigned short h1 = f2bf(xv.y); hv.y = h1; lv.y = f2bf(xv.y - bf2f(h1));
            unsigned short h2 = f2bf(xv.z); hv.z = h2; lv.z = f2bf(xv.z - bf2f(h2));
            unsigned short h3 = f2bf(xv.w); hv.w = h3; lv.w = f2bf(xv.w - bf2f(h3));
            *(u16x4*)&A_lds[xb][xd]       = hv;
            *(u16x4*)&A_lds[xb][128 + xd] = lv;
            int tn = (t + 1 < T_LEN) ? (t + 1) : (T_LEN - 1);
            xv = *(const float4*)(xptr + (size_t)tn * D_IN);
        }
        // gather partners' h[t-1] (wave w handles partner (j+w)&7; wave 0 idle).
        // RELAXED-only protocol: no acquire/release -> no buffer_inv / L2 writeback.
        // Visibility: publisher drained data to LLC (vmcnt(0)) BEFORE flag store;
        // our data loads issue after the poll load completes (control dep + waitcnt),
        // and sc1 agent loads read the LLC directly (no stale L1/L2).
        if (t > 0 && w > 0) {
            const int pj = (j + w) & 7;
            const unsigned int* pf = flags + (size_t)(g * 8 + pj) * 16;
            if (lane < 8) {
                while (__hip_atomic_load(&pf[lane], __ATOMIC_RELAXED,
                                         __HIP_MEMORY_SCOPE_AGENT) < (unsigned)t) { }
            }
            asm volatile("" ::: "memory");      // keep data loads below the poll
            const u64* hb = hbuf + ((size_t)((t - 1) & 1) * 64 + g * 8 + pj) * 128;
            u64 v0 = __hip_atomic_load(&hb[lane],      __ATOMIC_RELAXED, __HIP_MEMORY_SCOPE_AGENT);
            u64 v1 = __hip_atomic_load(&hb[64 + lane], __ATOMIC_RELAXED, __HIP_MEMORY_SCOPE_AGENT);
            *(u64*)&A_lds[lane >> 3][256 + 32 * pj + 4 * (lane & 7)]       = v0;
            *(u64*)&A_lds[8 + (lane >> 3)][256 + 32 * pj + 4 * (lane & 7)] = v1;
        }
        __syncthreads();

        // A-frags (shared by all waves) + MFMA from AGPR-resident weights
        s16x8 a[16];
#pragma unroll
        for (int at = 0; at < 16; ++at)
            a[at] = *(const s16x8*)&A_lds[mrow][at * 32 + kq * 8];
        f32x4 acc = { bias_r, bias_r, bias_r, bias_r };
#pragma unroll
        for (int q = 0; q < 4; ++q) {
            MFMA_A(a[q], Bf[q]);            // x_hi * Wx_hi
            MFMA_A(a[4 + q], Bf[q]);        // x_lo * Wx_hi
            MFMA_A(a[q], Bf[4 + q]);        // x_hi * Wx_lo
        }
#pragma unroll
        for (int q = 8; q < 16; ++q) MFMA_A(a[q], Bf[q]);   // h * Wh
        asm volatile("s_nop 7\n\ts_nop 7" ::: );
#pragma unroll
        for (int r = 0; r < 4; ++r)
            gate_lds[kq * 4 + r][w * 16 + mrow] = acc[r];
        __syncthreads();

        // elementwise cell update (c thread-private fp32)
        float pg  = gate_lds[b_e][u_e];
        float pi  = gate_lds[b_e][32 + u_e];
        float pff = gate_lds[b_e][64 + u_e];
        float po  = gate_lds[b_e][96 + u_e];
        c_reg = ftanh(pg) * fsig(pi) + c_reg * fsig(pff);
        float h = ftanh(c_reg) * fsig(po);
        unsigned int hb16 = f2bf(h);
        A_lds[b_e][256 + 32 * j + u_e] = (unsigned short)hb16;

        // pack 4 lanes -> u64, publish own slice (relaxed agent), drain, then flag
        unsigned int p01 = hb16 | (((unsigned int)__shfl_down((int)hb16, 1)) << 16);
        unsigned int p23 = (unsigned int)__shfl_down((int)p01, 2);
        u64 val = (u64)p01 | ((u64)p23 << 32);
        if ((lane & 3) == 0) {
            u64* dst = hbuf + ((size_t)(t & 1) * 64 + g * 8 + j) * 128 + (b_e * 8 + (u_e >> 2));
            __hip_atomic_store(dst, val, __ATOMIC_RELAXED, __HIP_MEMORY_SCOPE_AGENT);
        }
        asm volatile("s_waitcnt vmcnt(0)" ::: "memory");   // data at LLC before flag
        if (lane == 0)
            __hip_atomic_store(myflag, (unsigned int)(t + 1), __ATOMIC_RELAXED,
                               __HIP_MEMORY_SCOPE_AGENT);
    }
    __syncthreads();

    // projection partial over own 32 units -> atomicAdd into bias-initialized out
    if (tid < BB * NCLS) {
        int b = tid / NCLS, cls = tid - b * NCLS;
        float s = 0.0f;
#pragma unroll
        for (int u = 0; u < 32; ++u)
            s += bf2f(A_lds[b][256 + 32 * j + u]) * Wph[(32 * j + u) * NCLS + cls];
        atomicAdd(&out[(g * BB + b) * NCLS + cls], s);
    }
}

extern "C" void kernel_launch(void* const* d_in, const int* in_sizes, int n_in,
                              void* d_out, int out_size, void* d_ws, size_t ws_size,
                              hipStream_t stream) {
    const float* x   = (const float*)d_in[0];
    const float* Wgx = (const float*)d_in[1];
    const float* Wgh = (const float*)d_in[2];
    const float* bg  = (const float*)d_in[3];
    const float* Wix = (const float*)d_in[4];
    const float* Wih = (const float*)d_in[5];
    const float* bi  = (const float*)d_in[6];
    const float* Wfx = (const float*)d_in[7];
    const float* Wfh = (const float*)d_in[8];
    const float* bf_ = (const float*)d_in[9];
    const float* Wox = (const float*)d_in[10];
    const float* Woh = (const float*)d_in[11];
    const float* bo  = (const float*)d_in[12];
    const float* Wph = (const float*)d_in[13];
    const float* bp  = (const float*)d_in[14];

    unsigned short* WT  = (unsigned short*)d_ws;
    float* bias_ws      = (float*)((char*)d_ws + BIAS_OFF);
    unsigned int* flags = (unsigned int*)((char*)d_ws + FLAGS_OFF);
    u64* hbuf           = (u64*)((char*)d_ws + HBUF_OFF);

    prep_kernel<<<256, 256, 0, stream>>>(
        Wgx, Wix, Wfx, Wox, Wgh, Wih, Wfh, Woh, bg, bi, bf_, bo, bp,
        WT, bias_ws, flags, (float*)d_out);
    lstm_kernel<<<NGRP * NCB, 512, 0, stream>>>(
        x, WT, bias_ws, Wph, flags, hbuf, (float*)d_out);
}